// Round 6
// baseline (177.187 us; speedup 1.0000x reference)
//
#include <hip/hip_runtime.h>

#define B_DIM 2
#define H_DIM 16
#define S_DIM 2048
#define D_DIM 64

constexpr int QB = 128;            // q rows per block (4 waves x 32)
constexpr int KB = 128;            // keys per barrier round (2 x 64-key halves)
constexpr int NR = S_DIM / KB;     // 16 rounds
constexpr float CL2E = 0.18033688011112042f;  // (1/sqrt(64)) * log2(e)

typedef __attribute__((ext_vector_type(8))) short short8;   // 8 bf16
typedef __attribute__((ext_vector_type(4))) float f32x4;
typedef __attribute__((ext_vector_type(2))) unsigned uint2v;

__device__ __forceinline__ unsigned pkbf(float lo, float hi) {
  unsigned r;
  asm("v_cvt_pk_bf16_f32 %0, %1, %2" : "=v"(r) : "v"(lo), "v"(hi));
  return r;
}

__device__ __forceinline__ float fexp2(float x) {
  float r;
  asm("v_exp_f32 %0, %1" : "=v"(r) : "v"(x));
  return r;
}

// drain LDS ops (cross-wave visibility) but NOT vmcnt — prefetch global
// loads stay in flight across the barrier (T14).
__device__ __forceinline__ void barrier_lds() {
  asm volatile("s_waitcnt lgkmcnt(0)" ::: "memory");
  __builtin_amdgcn_s_barrier();
  asm volatile("" ::: "memory");
}

__global__ __launch_bounds__(256, 2)
void sdpa_kernel(const float* __restrict__ Qp, const float* __restrict__ Kp,
                 const float* __restrict__ Vp, const int* __restrict__ maskp,
                 float* __restrict__ ctx, float* __restrict__ attn)
{
  __shared__ __align__(16) unsigned short sK[2][KB * 64];   // [buf][key][d] bf16, swizzled
  __shared__ __align__(16) unsigned short sV[2][64 * KB];   // [buf][d][key] bf16, swizzled
  __shared__ __align__(16) unsigned short sP[4][32 * 64];   // per-wave P [q][key64] bf16, reused per half

  const int tid  = threadIdx.x;
  const int wave = tid >> 6;
  const int lane = tid & 63;
  const int c = lane & 15;      // fragment col (q within 16)
  const int g = lane >> 4;      // fragment key-subgroup

  // XCD-aware bijective swizzle (512 % 8 == 0)
  const int bid = (blockIdx.x & 7) * 64 + (blockIdx.x >> 3);
  const int bh = bid >> 4;
  const int qt = bid & 15;
  const int q0 = qt * QB + wave * 32;
  const size_t bhS = (size_t)bh * S_DIM;

  // staging coords
  const int keyk  = tid >> 1;             // K: 0..127
  const int dhalf = (tid & 1) << 5;       // K: 0 or 32 (elements)
  const int kp    = (tid & 63) << 1;      // V: even key 0..126
  const int dg    = (tid >> 6) << 3;      // V: d octet base 0,8,16,24 (+0/+32)

  // ---- Q fragments (B-operand): col=q=lane&15, k = kk*32 + g*8 + j ----
  short8 qf[2][2];
  #pragma unroll
  for (int m = 0; m < 2; ++m)
    #pragma unroll
    for (int kk = 0; kk < 2; ++kk) {
      const float* src = Qp + (bhS + (size_t)(q0 + m*16 + c)) * D_DIM + kk*32 + g*8;
      float4 a = ((const float4*)src)[0];
      float4 b = ((const float4*)src)[1];
      union { unsigned u[4]; short8 s; } w;
      w.u[0] = pkbf(a.x, a.y); w.u[1] = pkbf(a.z, a.w);
      w.u[2] = pkbf(b.x, b.y); w.u[3] = pkbf(b.z, b.w);
      qf[m][kk] = w.s;
    }

  // row(q)-mask * scale * log2e
  float rvS[2];
  #pragma unroll
  for (int m = 0; m < 2; ++m)
    rvS[m] = maskp[bhS + q0 + m*16 + c] ? CL2E : 0.0f;

  // prefetch registers
  float4 kr[8];
  float4 vr[8];
  unsigned mb[2];     // packed col-mask bits, bit (n*4+e), per half

  auto load_k = [&](int kt_) {
    const float* s = Kp + (bhS + (size_t)(kt_ * KB + keyk)) * D_DIM + dhalf;
    #pragma unroll
    for (int i = 0; i < 8; ++i) kr[i] = ((const float4*)s)[i];
  };
  auto load_v = [&](int kt_) {
    const float* s0 = Vp + (bhS + (size_t)(kt_ * KB + kp)) * D_DIM + dg;
    vr[0] = ((const float4*)s0)[0];      vr[1] = ((const float4*)s0)[1];
    vr[2] = ((const float4*)(s0+32))[0]; vr[3] = ((const float4*)(s0+32))[1];
    const float* s1 = s0 + D_DIM;
    vr[4] = ((const float4*)s1)[0];      vr[5] = ((const float4*)s1)[1];
    vr[6] = ((const float4*)(s1+32))[0]; vr[7] = ((const float4*)(s1+32))[1];
  };
  auto load_mb = [&](int kt_) {
    #pragma unroll
    for (int hh = 0; hh < 2; ++hh) {
      unsigned m = 0;
      #pragma unroll
      for (int n = 0; n < 4; ++n) {
        int4 v = *(const int4*)&maskp[bhS + kt_*KB + hh*64 + n*16 + g*4];
        m |= (v.x & 1u) << (n*4 + 0);
        m |= (v.y & 1u) << (n*4 + 1);
        m |= (v.z & 1u) << (n*4 + 2);
        m |= (v.w & 1u) << (n*4 + 3);
      }
      mb[hh] = m;
    }
  };
  auto write_k = [&](int buf) {
    const int sw = (keyk & 7) << 3;
    #pragma unroll
    for (int o = 0; o < 4; ++o) {
      const float* f = (const float*)&kr[o*2];
      union { unsigned u[4]; short8 s; } w;
      w.u[0] = pkbf(f[0], f[1]); w.u[1] = pkbf(f[2], f[3]);
      w.u[2] = pkbf(f[4], f[5]); w.u[3] = pkbf(f[6], f[7]);
      *(short8*)&sK[buf][keyk * 64 + ((dhalf + o*8) ^ sw)] = w.s;
    }
  };
  auto write_v = [&](int buf) {
    float av[16], bv[16];
    *(float4*)&av[0]  = vr[0]; *(float4*)&av[4]  = vr[1];
    *(float4*)&av[8]  = vr[2]; *(float4*)&av[12] = vr[3];
    *(float4*)&bv[0]  = vr[4]; *(float4*)&bv[4]  = vr[5];
    *(float4*)&bv[8]  = vr[6]; *(float4*)&bv[12] = vr[7];
    #pragma unroll
    for (int e = 0; e < 16; ++e) {
      const int d = dg + (e & 7) + ((e & 8) ? 32 : 0);
      *(unsigned*)&sV[buf][d * KB + (kp ^ ((d & 15) << 3))] = pkbf(av[e], bv[e]);
    }
  };

  float lsum[2] = {0.0f, 0.0f};

  // ================= pass 1: row sums of exp(s) =================
  load_k(0);
  for (int r = 0; r < NR; ++r) {
    const int cur = r & 1;
    write_k(cur);
    load_mb(r);
    if (r + 1 < NR) load_k(r + 1);
    barrier_lds();

    #pragma unroll
    for (int h = 0; h < 2; ++h) {
      short8 kf[4][2];
      #pragma unroll
      for (int n = 0; n < 4; ++n) {
        const int k2 = h*64 + n*16 + c;
        const int sw = (c & 7) << 3;
        #pragma unroll
        for (int kk = 0; kk < 2; ++kk)
          kf[n][kk] = *(const short8*)&sK[cur][k2*64 + ((kk*32 + g*8) ^ sw)];
      }
      f32x4 sacc[4][2];
      #pragma unroll
      for (int n = 0; n < 4; ++n)
        #pragma unroll
        for (int m = 0; m < 2; ++m) sacc[n][m] = 0.0f;
      __builtin_amdgcn_s_setprio(1);
      #pragma unroll
      for (int n = 0; n < 4; ++n)
        #pragma unroll
        for (int m = 0; m < 2; ++m)
          #pragma unroll
          for (int kk = 0; kk < 2; ++kk)
            sacc[n][m] = __builtin_amdgcn_mfma_f32_16x16x32_bf16(kf[n][kk], qf[m][kk], sacc[n][m], 0, 0, 0);
      __builtin_amdgcn_s_setprio(0);

      #pragma unroll
      for (int m = 0; m < 2; ++m)
        #pragma unroll
        for (int n = 0; n < 4; ++n)
          #pragma unroll
          for (int e = 0; e < 4; ++e) {
            const float cf = (float)((mb[h] >> (n*4 + e)) & 1u);
            lsum[m] += fexp2(sacc[n][m][e] * (cf * rvS[m]));
          }
    }
  }

  // reduce over the 4 key-subgroups -> log2 of reciprocal row sum
  float Lm[2];
  #pragma unroll
  for (int m = 0; m < 2; ++m) {
    float v = lsum[m];
    v += __shfl_xor(v, 16);
    v += __shfl_xor(v, 32);
    Lm[m] = -__log2f(v);
  }

  // ================= pass 2: recompute, write attn, PV =================
  f32x4 oacc[2][4];
  #pragma unroll
  for (int m = 0; m < 2; ++m)
    #pragma unroll
    for (int n = 0; n < 4; ++n) oacc[m][n] = 0.0f;

  unsigned short* const myP = sP[wave];
  const int rh  = lane >> 4;
  const int c16 = lane & 15;
  float* const abase = attn + (bhS + (size_t)q0) * S_DIM;

  load_k(0); load_v(0);
  for (int r = 0; r < NR; ++r) {
    const int cur = r & 1;
    write_k(cur);
    write_v(cur);
    load_mb(r);
    if (r + 1 < NR) { load_k(r + 1); load_v(r + 1); }
    barrier_lds();

    #pragma unroll
    for (int h = 0; h < 2; ++h) {
      short8 kf[4][2];
      #pragma unroll
      for (int n = 0; n < 4; ++n) {
        const int k2 = h*64 + n*16 + c;
        const int sw = (c & 7) << 3;
        #pragma unroll
        for (int kk = 0; kk < 2; ++kk)
          kf[n][kk] = *(const short8*)&sK[cur][k2*64 + ((kk*32 + g*8) ^ sw)];
      }
      f32x4 sacc[4][2];
      #pragma unroll
      for (int n = 0; n < 4; ++n)
        #pragma unroll
        for (int m = 0; m < 2; ++m) sacc[n][m] = 0.0f;
      __builtin_amdgcn_s_setprio(1);
      #pragma unroll
      for (int n = 0; n < 4; ++n)
        #pragma unroll
        for (int m = 0; m < 2; ++m)
          #pragma unroll
          for (int kk = 0; kk < 2; ++kk)
            sacc[n][m] = __builtin_amdgcn_mfma_f32_16x16x32_bf16(kf[n][kk], qf[m][kk], sacc[n][m], 0, 0, 0);
      __builtin_amdgcn_s_setprio(0);

      // p = exp2(s*comb + Lm) -> bf16 into wave-private sP (swizzled)
      #pragma unroll
      for (int m = 0; m < 2; ++m) {
        #pragma unroll
        for (int n = 0; n < 4; ++n) {
          f32x4 pv;
          #pragma unroll
          for (int e = 0; e < 4; ++e) {
            const float cf = (float)((mb[h] >> (n*4 + e)) & 1u);
            pv[e] = fexp2(__builtin_fmaf(sacc[n][m][e], cf * rvS[m], Lm[m]));
          }
          const int row = m*16 + c;
          const int swk = (n*16 + g*4) ^ ((c & 7) << 3);
          uint2v pr; pr.x = pkbf(pv[0], pv[1]); pr.y = pkbf(pv[2], pv[3]);
          *(uint2v*)&myP[row*64 + swk] = pr;
        }
      }

      // PV: A = P[q][key] from sP, B = V[key][d] from transposed sV
      short8 pf[2][2];
      #pragma unroll
      for (int m = 0; m < 2; ++m) {
        const int row = m*16 + c;
        const int sw = (c & 7) << 3;
        #pragma unroll
        for (int kk = 0; kk < 2; ++kk)
          pf[m][kk] = *(const short8*)&myP[row*64 + ((kk*32 + g*8) ^ sw)];
      }
      short8 vf[4][2];
      #pragma unroll
      for (int n = 0; n < 4; ++n) {
        const int d = n*16 + c;
        #pragma unroll
        for (int kk = 0; kk < 2; ++kk)
          vf[n][kk] = *(const short8*)&sV[cur][d*KB + ((h*64 + kk*32 + g*8) ^ (c << 3))];
      }
      __builtin_amdgcn_s_setprio(1);
      #pragma unroll
      for (int m = 0; m < 2; ++m)
        #pragma unroll
        for (int n = 0; n < 4; ++n)
          #pragma unroll
          for (int kk = 0; kk < 2; ++kk)
            oacc[m][n] = __builtin_amdgcn_mfma_f32_16x16x32_bf16(pf[m][kk], vf[n][kk], oacc[m][n], 0, 0, 0);
      __builtin_amdgcn_s_setprio(0);

      // attn copy-out from sP: each store = 4 rows x 256B = 1KB contiguous
      {
        float* const at = abase + r*KB + h*64;
        #pragma unroll
        for (int j = 0; j < 8; ++j) {
          const int rr = j*4 + rh;
          const int p8 = (c16 >> 1) ^ (rr & 7);
          uint2v u = *(const uint2v*)&myP[rr*64 + p8*8 + (c16 & 1)*4];
          union { unsigned iu; float f; } t0, t1, t2, t3;
          t0.iu = u.x << 16; t1.iu = u.x & 0xFFFF0000u;
          t2.iu = u.y << 16; t3.iu = u.y & 0xFFFF0000u;
          f32x4 o; o[0] = t0.f; o[1] = t1.f; o[2] = t2.f; o[3] = t3.f;
          __builtin_nontemporal_store(o, (f32x4*)(at + (size_t)rr * S_DIM + c16*4));
        }
      }
    }
  }

  // context write
  #pragma unroll
  for (int m = 0; m < 2; ++m)
    #pragma unroll
    for (int n = 0; n < 4; ++n)
      #pragma unroll
      for (int e = 0; e < 4; ++e) {
        const int rl = m*16 + g*4 + e;
        ctx[(bhS + (size_t)(q0 + rl)) * D_DIM + (size_t)(n*16 + c)] = oacc[m][n][e];
      }
}

extern "C" void kernel_launch(void* const* d_in, const int* in_sizes, int n_in,
                              void* d_out, int out_size, void* d_ws, size_t ws_size,
                              hipStream_t stream) {
  const float* Q = (const float*)d_in[0];
  const float* K = (const float*)d_in[1];
  const float* V = (const float*)d_in[2];
  const int*   M = (const int*)d_in[3];
  float* ctx  = (float*)d_out;
  float* attn = ctx + (size_t)B_DIM * H_DIM * S_DIM * D_DIM;
  dim3 grid(B_DIM * H_DIM * (S_DIM / QB));   // 512 blocks
  sdpa_kernel<<<grid, 256, 0, stream>>>(Q, K, V, M, ctx, attn);
}

// Round 7
// 152.916 us; speedup vs baseline: 1.1587x; 1.1587x over previous
//
#include <hip/hip_runtime.h>

#define B_DIM 2
#define H_DIM 16
#define S_DIM 2048
#define D_DIM 64

constexpr int QB = 128;            // q rows per block (4 waves x 32)
constexpr int KB = 64;             // keys per tile
constexpr int NT = S_DIM / KB;     // 32 key tiles
constexpr float CL2E = 0.18033688011112042f;  // (1/sqrt(64)) * log2(e)

typedef __attribute__((ext_vector_type(8))) short short8;   // 8 bf16
typedef __attribute__((ext_vector_type(4))) float f32x4;
typedef __attribute__((ext_vector_type(2))) unsigned uint2v;

__device__ __forceinline__ unsigned pkbf(float lo, float hi) {
  unsigned r;
  asm("v_cvt_pk_bf16_f32 %0, %1, %2" : "=v"(r) : "v"(lo), "v"(hi));
  return r;
}

__device__ __forceinline__ float fexp2(float x) {
  float r;
  asm("v_exp_f32 %0, %1" : "=v"(r) : "v"(x));
  return r;
}

// drain LDS ops (cross-wave visibility) but NOT vmcnt — prefetch global
// loads stay in flight across the barrier (T14).
__device__ __forceinline__ void barrier_lds() {
  asm volatile("s_waitcnt lgkmcnt(0)" ::: "memory");
  __builtin_amdgcn_s_barrier();
  asm volatile("" ::: "memory");
}

__global__ __launch_bounds__(256, 2)
void sdpa_kernel(const float* __restrict__ Qp, const float* __restrict__ Kp,
                 const float* __restrict__ Vp, const int* __restrict__ maskp,
                 float* __restrict__ ctx, float* __restrict__ attn)
{
  __shared__ __align__(16) unsigned short sK[2][KB * 64];      // [buf][key][d] bf16, swizzled, col-masked
  __shared__ __align__(16) unsigned short sV[2][64 * KB];      // [buf][d][key] bf16, swizzled
  __shared__ __align__(16) unsigned short sP[2][4][32 * 64];   // [buf][wave] P [q][key] bf16, swizzled

  const int tid  = threadIdx.x;
  const int wave = tid >> 6;
  const int lane = tid & 63;
  const int c = lane & 15;      // fragment col (q within 16)
  const int g = lane >> 4;      // fragment key-subgroup

  // XCD-aware bijective swizzle (512 % 8 == 0)
  const int bid = (blockIdx.x & 7) * 64 + (blockIdx.x >> 3);
  const int bh = bid >> 4;
  const int qt = bid & 15;
  const int q0 = qt * QB + wave * 32;
  const size_t bhS = (size_t)bh * S_DIM;

  // staging coords
  const int key = tid >> 2;               // K: 0..63
  const int dq  = (tid & 3) << 4;         // K: 0,16,32,48
  const int kp  = (tid & 31) << 1;        // V: even key 0..62
  const int dq8 = (tid >> 5) << 3;        // V: d octet 0..56

  // ---- Q fragments (B-operand): col=q=lane&15, k = kk*32 + g*8 + j ----
  short8 qf[2][2];
  #pragma unroll
  for (int m = 0; m < 2; ++m)
    #pragma unroll
    for (int kk = 0; kk < 2; ++kk) {
      const float* src = Qp + (bhS + (size_t)(q0 + m*16 + c)) * D_DIM + kk*32 + g*8;
      float4 a = ((const float4*)src)[0];
      float4 b = ((const float4*)src)[1];
      union { unsigned u[4]; short8 s; } w;
      w.u[0] = pkbf(a.x, a.y); w.u[1] = pkbf(a.z, a.w);
      w.u[2] = pkbf(b.x, b.y); w.u[3] = pkbf(b.z, b.w);
      qf[m][kk] = w.s;
    }

  // row(q)-mask * scale * log2e
  float rvS[2];
  #pragma unroll
  for (int m = 0; m < 2; ++m)
    rvS[m] = maskp[bhS + q0 + m*16 + c] ? CL2E : 0.0f;

  // prefetch registers
  float4 kr0, kr1, kr2, kr3;
  float4 vA0, vA1, vB0, vB1;
  unsigned kmr;                 // col-mask for this thread's staged K row

  auto load_k = [&](int kt_) {
    const float* s = Kp + (bhS + (size_t)(kt_ * KB + key)) * D_DIM + dq;
    kr0 = ((const float4*)s)[0]; kr1 = ((const float4*)s)[1];
    kr2 = ((const float4*)s)[2]; kr3 = ((const float4*)s)[3];
    kmr = maskp[bhS + kt_ * KB + key] ? 0xFFFFFFFFu : 0u;
  };
  auto load_v = [&](int kt_) {
    const float* s0 = Vp + (bhS + (size_t)(kt_ * KB + kp)) * D_DIM + dq8;
    vA0 = ((const float4*)s0)[0]; vA1 = ((const float4*)s0)[1];
    vB0 = ((const float4*)(s0 + D_DIM))[0]; vB1 = ((const float4*)(s0 + D_DIM))[1];
  };
  // col-masked K staging: masked key rows are stored as exact zeros, so
  // sacc==0 for them and p = exp2(0 + Lm) = 1/sum — the reference's value.
  auto write_k = [&](int buf) {
    union { unsigned u[4]; short8 s; } w0, w1;
    w0.u[0] = pkbf(kr0.x, kr0.y) & kmr; w0.u[1] = pkbf(kr0.z, kr0.w) & kmr;
    w0.u[2] = pkbf(kr1.x, kr1.y) & kmr; w0.u[3] = pkbf(kr1.z, kr1.w) & kmr;
    w1.u[0] = pkbf(kr2.x, kr2.y) & kmr; w1.u[1] = pkbf(kr2.z, kr2.w) & kmr;
    w1.u[2] = pkbf(kr3.x, kr3.y) & kmr; w1.u[3] = pkbf(kr3.z, kr3.w) & kmr;
    const int sw = (key & 7) << 3;
    *(short8*)&sK[buf][key * 64 + (dq ^ sw)]       = w0.s;
    *(short8*)&sK[buf][key * 64 + ((dq + 8) ^ sw)] = w1.s;
  };
  auto write_v = [&](int buf) {
    float fa[8], fb[8];
    *(float4*)&fa[0] = vA0; *(float4*)&fa[4] = vA1;
    *(float4*)&fb[0] = vB0; *(float4*)&fb[4] = vB1;
    #pragma unroll
    for (int e = 0; e < 8; ++e) {
      const int d = dq8 + e;
      *(unsigned*)&sV[buf][d * KB + (kp ^ ((d & 7) << 3))] = pkbf(fa[e], fb[e]);
    }
  };

  float lsum[2] = {0.0f, 0.0f};

  // ================= pass 1: row sums of exp(s) =================
  load_k(0);
  for (int kt = 0; kt < NT; ++kt) {
    const int cur = kt & 1;
    write_k(cur);
    if (kt + 1 < NT) load_k(kt + 1);
    barrier_lds();

    short8 kf[4][2];
    #pragma unroll
    for (int n = 0; n < 4; ++n) {
      const int k2 = n*16 + c;
      const int sw = (c & 7) << 3;
      #pragma unroll
      for (int kk = 0; kk < 2; ++kk)
        kf[n][kk] = *(const short8*)&sK[cur][k2*64 + ((kk*32 + g*8) ^ sw)];
    }

    f32x4 sacc[4][2];   // [key-frag n][q-frag m]
    #pragma unroll
    for (int n = 0; n < 4; ++n)
      #pragma unroll
      for (int m = 0; m < 2; ++m) sacc[n][m] = 0.0f;
    __builtin_amdgcn_s_setprio(1);
    #pragma unroll
    for (int n = 0; n < 4; ++n)
      #pragma unroll
      for (int m = 0; m < 2; ++m)
        #pragma unroll
        for (int kk = 0; kk < 2; ++kk)
          sacc[n][m] = __builtin_amdgcn_mfma_f32_16x16x32_bf16(kf[n][kk], qf[m][kk], sacc[n][m], 0, 0, 0);
    __builtin_amdgcn_s_setprio(0);

    #pragma unroll
    for (int m = 0; m < 2; ++m)
      #pragma unroll
      for (int n = 0; n < 4; ++n)
        #pragma unroll
        for (int e = 0; e < 4; ++e)
          lsum[m] += fexp2(sacc[n][m][e] * rvS[m]);
  }

  // reduce over the 4 key-subgroups -> log2 of reciprocal row sum
  float Lm[2];
  #pragma unroll
  for (int m = 0; m < 2; ++m) {
    float v = lsum[m];
    v += __shfl_xor(v, 16);
    v += __shfl_xor(v, 32);
    Lm[m] = -__log2f(v);
  }

  // ================= pass 2: recompute, write attn, PV =================
  f32x4 oacc[2][4];
  #pragma unroll
  for (int m = 0; m < 2; ++m)
    #pragma unroll
    for (int n = 0; n < 4; ++n) oacc[m][n] = 0.0f;

  const int rh  = lane >> 4;
  const int c16 = lane & 15;
  float* const abase = attn + (bhS + (size_t)q0) * S_DIM;

  // attn copy-out from sP buf pb for tile kt_: 4 rows x 256B = 1KB per store
  auto copyout = [&](int pb, int kt_) {
    const unsigned short* const Pp = sP[pb][wave];
    float* const at = abase + kt_*KB;
    #pragma unroll
    for (int j = 0; j < 8; ++j) {
      const int rr = j*4 + rh;
      const int p8 = (c16 >> 1) ^ (rr & 7);
      uint2v u = *(const uint2v*)&Pp[rr*64 + p8*8 + (c16 & 1)*4];
      union { unsigned iu; float f; } t0, t1, t2, t3;
      t0.iu = u.x << 16; t1.iu = u.x & 0xFFFF0000u;
      t2.iu = u.y << 16; t3.iu = u.y & 0xFFFF0000u;
      f32x4 o; o[0] = t0.f; o[1] = t1.f; o[2] = t2.f; o[3] = t3.f;
      __builtin_nontemporal_store(o, (f32x4*)(at + (size_t)rr * S_DIM + c16*4));
    }
  };

  load_k(0); load_v(0);
  for (int kt = 0; kt < NT; ++kt) {
    const int cur = kt & 1;
    write_k(cur);
    write_v(cur);
    if (kt + 1 < NT) { load_k(kt + 1); load_v(kt + 1); }
    barrier_lds();

    short8 kf[4][2];
    #pragma unroll
    for (int n = 0; n < 4; ++n) {
      const int k2 = n*16 + c;
      const int sw = (c & 7) << 3;
      #pragma unroll
      for (int kk = 0; kk < 2; ++kk)
        kf[n][kk] = *(const short8*)&sK[cur][k2*64 + ((kk*32 + g*8) ^ sw)];
    }

    f32x4 sacc[4][2];
    #pragma unroll
    for (int n = 0; n < 4; ++n)
      #pragma unroll
      for (int m = 0; m < 2; ++m) sacc[n][m] = 0.0f;
    __builtin_amdgcn_s_setprio(1);
    #pragma unroll
    for (int n = 0; n < 4; ++n)
      #pragma unroll
      for (int m = 0; m < 2; ++m)
        #pragma unroll
        for (int kk = 0; kk < 2; ++kk)
          sacc[n][m] = __builtin_amdgcn_mfma_f32_16x16x32_bf16(kf[n][kk], qf[m][kk], sacc[n][m], 0, 0, 0);
    __builtin_amdgcn_s_setprio(0);

    // deferred copy-out of PREVIOUS tile's attn: stores drain under this
    // tile's epilogue + PV compute (sP double-buffered, wave-private)
    if (kt > 0) copyout(cur ^ 1, kt - 1);

    // p = exp2(s*rvS + Lm) -> bf16 into wave-private sP[cur] (swizzled)
    unsigned short* const myP = sP[cur][wave];
    #pragma unroll
    for (int m = 0; m < 2; ++m) {
      #pragma unroll
      for (int n = 0; n < 4; ++n) {
        f32x4 pv;
        #pragma unroll
        for (int e = 0; e < 4; ++e)
          pv[e] = fexp2(__builtin_fmaf(sacc[n][m][e], rvS[m], Lm[m]));
        const int row = m*16 + c;
        const int swk = (n*16 + g*4) ^ ((c & 7) << 3);
        uint2v pr; pr.x = pkbf(pv[0], pv[1]); pr.y = pkbf(pv[2], pv[3]);
        *(uint2v*)&myP[row*64 + swk] = pr;
      }
    }

    // PV: A = P[q][key] from sP, B = V[key][d] from transposed sV
    short8 pf[2][2];
    #pragma unroll
    for (int m = 0; m < 2; ++m) {
      const int row = m*16 + c;
      const int sw = (c & 7) << 3;
      #pragma unroll
      for (int kk = 0; kk < 2; ++kk)
        pf[m][kk] = *(const short8*)&myP[row*64 + ((kk*32 + g*8) ^ sw)];
    }
    short8 vf[4][2];
    #pragma unroll
    for (int n = 0; n < 4; ++n) {
      const int d = n*16 + c;
      const int sw = (d & 7) << 3;
      #pragma unroll
      for (int kk = 0; kk < 2; ++kk)
        vf[n][kk] = *(const short8*)&sV[cur][d*KB + ((kk*32 + g*8) ^ sw)];
    }
    __builtin_amdgcn_s_setprio(1);
    #pragma unroll
    for (int m = 0; m < 2; ++m)
      #pragma unroll
      for (int n = 0; n < 4; ++n)
        #pragma unroll
        for (int kk = 0; kk < 2; ++kk)
          oacc[m][n] = __builtin_amdgcn_mfma_f32_16x16x32_bf16(pf[m][kk], vf[n][kk], oacc[m][n], 0, 0, 0);
    __builtin_amdgcn_s_setprio(0);
  }

  // last tile's attn
  copyout((NT - 1) & 1, NT - 1);

  // context write
  #pragma unroll
  for (int m = 0; m < 2; ++m)
    #pragma unroll
    for (int n = 0; n < 4; ++n)
      #pragma unroll
      for (int e = 0; e < 4; ++e) {
        const int rl = m*16 + g*4 + e;
        ctx[(bhS + (size_t)(q0 + rl)) * D_DIM + (size_t)(n*16 + c)] = oacc[m][n][e];
      }
}

extern "C" void kernel_launch(void* const* d_in, const int* in_sizes, int n_in,
                              void* d_out, int out_size, void* d_ws, size_t ws_size,
                              hipStream_t stream) {
  const float* Q = (const float*)d_in[0];
  const float* K = (const float*)d_in[1];
  const float* V = (const float*)d_in[2];
  const int*   M = (const int*)d_in[3];
  float* ctx  = (float*)d_out;
  float* attn = ctx + (size_t)B_DIM * H_DIM * S_DIM * D_DIM;
  dim3 grid(B_DIM * H_DIM * (S_DIM / QB));   // 512 blocks
  sdpa_kernel<<<grid, 256, 0, stream>>>(Q, K, V, M, ctx, attn);
}